// Round 3
// baseline (632.905 us; speedup 1.0000x reference)
//
#include <hip/hip_runtime.h>
#include <hip/hip_bf16.h>

#define T_LEN 96
#define C_CH  66
#define FIN   7128   // 9*66*12
#define KPAD  7168   // 224*32
#define NFC1  1936
#define NPAD  2048
#define NCLS  14

typedef __bf16 bf16x8 __attribute__((ext_vector_type(8)));
typedef float  f32x4  __attribute__((ext_vector_type(4)));

#define GLD_LDS(gp, lp) __builtin_amdgcn_global_load_lds(                     \
    (__attribute__((address_space(1))) void*)(gp),                            \
    (__attribute__((address_space(3))) void*)(lp), 16, 0, 0)

// wave-local LDS fence: all prior ds ops complete before later ones issue
__device__ __forceinline__ void wsync() {
    __asm__ volatile("s_waitcnt lgkmcnt(0)" ::: "memory");
}

// ---------------------------------------------------------------------------
// Kernel 1: w_fc1 (1936 x 7128 fp32) -> bf16 (2048 x 7168), zero padded.
__global__ __launch_bounds__(256) void pad_w_kernel(
    const float* __restrict__ w, __hip_bfloat16* __restrict__ wb)
{
    int idx = blockIdx.x * 256 + threadIdx.x;     // chunk id, total 2048*896
    int row = idx / 896;
    int cc  = idx - row * 896;                    // 896 chunks of 8 per row
    float4 a = {0.f, 0.f, 0.f, 0.f}, b = {0.f, 0.f, 0.f, 0.f};
    if (row < NFC1 && cc < 891) {                 // 891*8 = 7128
        const float4* src = (const float4*)(w + (size_t)row * FIN + cc * 8);
        a = src[0];
        b = src[1];
    }
    __align__(16) __hip_bfloat16 v[8];
    v[0] = __float2bfloat16(a.x); v[1] = __float2bfloat16(a.y);
    v[2] = __float2bfloat16(a.z); v[3] = __float2bfloat16(a.w);
    v[4] = __float2bfloat16(b.x); v[5] = __float2bfloat16(b.y);
    v[6] = __float2bfloat16(b.z); v[7] = __float2bfloat16(b.w);
    *(int4*)(wb + (size_t)row * KPAD + cc * 8) = *(const int4*)v;
}

// ---------------------------------------------------------------------------
// Kernel 2: feature extraction. One block per batch b; 4 waves; each wave
// owns channels ci = wid, wid+4, ... Lanes map to POSITIONS only, so every
// weight index is wave-uniform -> s_load into SGPRs (zero per-lane weight
// traffic). Pooling via shfl_down(1). Per-wave LDS slices, wave-local sync.
template <int K>
__device__ __forceinline__ void run_branch(
    int lane, const float* xbp, float* s1p, float* s2p,
    const float* __restrict__ wS, const float* __restrict__ bS,
    const float* __restrict__ wi1, const float* __restrict__ bi1,
    const float* __restrict__ wi2, const float* __restrict__ bi2,
    __hip_bfloat16* __restrict__ outp)
{
    constexpr int PAD = K / 2;
    wsync();

    // stage 1: shared conv (1->8, len 96) + relu + pool2 -> s1p[8][48]
    // chunk A: p = lane (64 pos); chunk B: p = 64+lane (32 pos, lane<32)
    {
        // chunk A
        {
            const int p = lane;
            float win[K + 1];
            #pragma unroll
            for (int k = 0; k <= K; k++) win[k] = xbp[(3 - PAD) + p + k];
            #pragma unroll
            for (int oc = 0; oc < 8; oc++) {
                float y = bS[oc];
                #pragma unroll
                for (int k = 0; k < K; k++) y = fmaf(wS[oc * K + k], win[k], y);
                float v  = fmaxf(y, 0.f);
                float v2 = __shfl_down(v, 1, 64);
                if ((p & 1) == 0) s1p[oc * 56 + 3 + (p >> 1)] = 0.5f * (v + v2);
            }
        }
        // chunk B
        if (lane < 32) {
            const int p = 64 + lane;
            float win[K];
            #pragma unroll
            for (int k = 0; k < K; k++) win[k] = xbp[(3 - PAD) + p + k];
            #pragma unroll
            for (int oc = 0; oc < 8; oc++) {
                float y = bS[oc];
                #pragma unroll
                for (int k = 0; k < K; k++) y = fmaf(wS[oc * K + k], win[k], y);
                float v  = fmaxf(y, 0.f);
                float v2 = __shfl_down(v, 1, 64);
                if ((p & 1) == 0) s1p[oc * 56 + 3 + (p >> 1)] = 0.5f * (v + v2);
            }
        }
    }
    wsync();

    // stage 2: grouped conv (8->4, len 48) + relu + pool2 -> s2p[4][24]
    // lane = position p (48 active); all 4 oc x 8 ic per lane, weights SGPR.
    {
        const int p = lane;
        float a[4];
        #pragma unroll
        for (int oc = 0; oc < 4; oc++) a[oc] = bi1[oc];
        if (p < 48) {
            #pragma unroll
            for (int ic = 0; ic < 8; ic++) {
                float win[K];
                #pragma unroll
                for (int k = 0; k < K; k++)
                    win[k] = s1p[ic * 56 + (3 - PAD) + p + k];
                #pragma unroll
                for (int oc = 0; oc < 4; oc++)
                    #pragma unroll
                    for (int k = 0; k < K; k++)
                        a[oc] = fmaf(wi1[(oc * 8 + ic) * K + k], win[k], a[oc]);
            }
        }
        #pragma unroll
        for (int oc = 0; oc < 4; oc++) {
            float v  = fmaxf(a[oc], 0.f);
            float v2 = __shfl_down(v, 1, 64);
            if (p < 48 && (p & 1) == 0)
                s2p[oc * 32 + 3 + (p >> 1)] = 0.5f * (v + v2);
        }
    }
    wsync();

    // stage 3: grouped conv (4->4, len 24) + relu + pool2 -> out[4][12] bf16
    {
        const int p = lane;
        float a[4];
        #pragma unroll
        for (int oc = 0; oc < 4; oc++) a[oc] = bi2[oc];
        if (p < 24) {
            #pragma unroll
            for (int ic = 0; ic < 4; ic++) {
                float win[K];
                #pragma unroll
                for (int k = 0; k < K; k++)
                    win[k] = s2p[ic * 32 + (3 - PAD) + p + k];
                #pragma unroll
                for (int oc = 0; oc < 4; oc++)
                    #pragma unroll
                    for (int k = 0; k < K; k++)
                        a[oc] = fmaf(wi2[(oc * 4 + ic) * K + k], win[k], a[oc]);
            }
        }
        #pragma unroll
        for (int oc = 0; oc < 4; oc++) {
            float v  = fmaxf(a[oc], 0.f);
            float v2 = __shfl_down(v, 1, 64);
            if (p < 24 && (p & 1) == 0)
                outp[oc * 12 + (p >> 1)] = __float2bfloat16(0.5f * (v + v2));
        }
    }
}

__global__ __launch_bounds__(256, 4) void feat_kernel(
    const float* __restrict__ x,
    const float* __restrict__ w_hs, const float* __restrict__ b_hs,
    const float* __restrict__ w_ls, const float* __restrict__ b_ls,
    const float* __restrict__ w_hi1, const float* __restrict__ b_hi1,
    const float* __restrict__ w_hi2, const float* __restrict__ b_hi2,
    const float* __restrict__ w_li1, const float* __restrict__ b_li1,
    const float* __restrict__ w_li2, const float* __restrict__ b_li2,
    __hip_bfloat16* __restrict__ feat)
{
    __shared__ __align__(16) float xt[6400];       // x[b] as (t,c), 96*66
    __shared__ __align__(16) float xbp_s[4][104];  // per-wave chan row, halo 3
    __shared__ __align__(16) float s1p_s[4][448];  // 8 rows, stride 56, halo 3
    __shared__ __align__(16) float s2p_s[4][128];  // 4 rows, stride 32, halo 3

    const int tid  = threadIdx.x;
    const int lane = tid & 63;
    const int wid  = tid >> 6;
    const int b    = blockIdx.x;

    // stage x[b] (6336 contiguous floats) into LDS: 24 full rounds + tail
    const float* xb = x + (size_t)b * (T_LEN * C_CH);
    for (int r = wid; r < 24; r += 4)
        GLD_LDS(xb + r * 256 + lane * 4, xt + r * 256);
    if (wid == 0 && lane < 48)
        GLD_LDS(xb + 6144 + lane * 4, xt + 6144);

    float* xbp = xbp_s[wid];
    float* s1p = s1p_s[wid];
    float* s2p = s2p_s[wid];
    // zero once: halos persist, interiors overwritten every channel
    for (int i = lane; i < 104; i += 64) xbp[i] = 0.f;
    for (int i = lane; i < 448; i += 64) s1p[i] = 0.f;
    for (int i = lane; i < 128; i += 64) s2p[i] = 0.f;
    __syncthreads();   // xt ready (vmcnt drained by barrier)

    __hip_bfloat16* out_base = feat + (size_t)b * KPAD;

    for (int ci0 = wid; ci0 < C_CH; ci0 += 4) {
        const int c = __builtin_amdgcn_readfirstlane(ci0);
        wsync();                                   // prior reads of xbp done
        xbp[3 + lane] = xt[lane * 66 + c];
        if (lane < 32) xbp[3 + 64 + lane] = xt[(64 + lane) * 66 + c];
        wsync();

        __hip_bfloat16* frow = out_base + c * 108;

        // orig = pool2^3 = mean of 8 consecutive
        if (lane < 12) {
            float s = 0.f;
            #pragma unroll
            for (int k = 0; k < 8; k++) s += xbp[3 + lane * 8 + k];
            frow[lane] = __float2bfloat16(s * 0.125f);
        }
        // zero the K padding of this batch row once
        if (c == 0 && lane < (KPAD - FIN))
            out_base[FIN + lane] = __float2bfloat16(0.f);

        run_branch<7>(lane, xbp, s1p, s2p, w_hs, b_hs,
                      w_hi1 + c * 224, b_hi1 + c * 4,
                      w_hi2 + c * 112, b_hi2 + c * 4, frow + 60); // high j=5..8
        run_branch<3>(lane, xbp, s1p, s2p, w_ls, b_ls,
                      w_li1 + c * 96, b_li1 + c * 4,
                      w_li2 + c * 48, b_li2 + c * 4, frow + 12);  // low j=1..4
    }
}

// ---------------------------------------------------------------------------
// Kernel 3: FC1 GEMM, A(2048xKPAD bf16) * W(2048xKPAD bf16)^T, split-K,
// plain fp32 stores into slabs (no atomics); bias/relu/reduce in fc2.
__global__ __launch_bounds__(256) void gemm_kernel(
    const __hip_bfloat16* __restrict__ A,
    const __hip_bfloat16* __restrict__ Bw,
    float* __restrict__ Cm, int kchunk)
{
    __shared__ __align__(16) __hip_bfloat16 As[4096];  // 128 x 32
    __shared__ __align__(16) __hip_bfloat16 Bs[4096];  // 128 x 32

    const int tid  = threadIdx.x;
    const int lane = tid & 63;
    const int wid  = tid >> 6;
    const int m0 = blockIdx.y * 128;
    const int n0 = blockIdx.x * 128;
    const int wm = (wid >> 1) * 64;
    const int wn = (wid & 1) * 64;
    const int lr = lane & 15;
    const int quad = lane >> 4;

    const int r0 = tid >> 2, c0 = (tid & 3) * 8;
    const __hip_bfloat16* gA0 = A  + (size_t)(m0 + r0) * KPAD + c0;
    const __hip_bfloat16* gA1 = gA0 + (size_t)64 * KPAD;
    const __hip_bfloat16* gB0 = Bw + (size_t)(n0 + r0) * KPAD + c0;
    const __hip_bfloat16* gB1 = gB0 + (size_t)64 * KPAD;
    __hip_bfloat16* lA0 = As + wid * 512;
    __hip_bfloat16* lA1 = As + 2048 + wid * 512;
    __hip_bfloat16* lB0 = Bs + wid * 512;
    __hip_bfloat16* lB1 = Bs + 2048 + wid * 512;

    f32x4 acc[4][4] = {};

    const int kBeg = blockIdx.z * kchunk;
    const int kEnd = kBeg + kchunk;
    for (int k0 = kBeg; k0 < kEnd; k0 += 32) {
        __syncthreads();
        GLD_LDS(gA0 + k0, lA0);
        GLD_LDS(gA1 + k0, lA1);
        GLD_LDS(gB0 + k0, lB0);
        GLD_LDS(gB1 + k0, lB1);
        __syncthreads();
        bf16x8 af[4], bfr[4];
        #pragma unroll
        for (int mt = 0; mt < 4; mt++)
            af[mt] = *(const bf16x8*)(As + (wm + mt * 16 + lr) * 32 + quad * 8);
        #pragma unroll
        for (int nt = 0; nt < 4; nt++)
            bfr[nt] = *(const bf16x8*)(Bs + (wn + nt * 16 + lr) * 32 + quad * 8);
        #pragma unroll
        for (int mt = 0; mt < 4; mt++)
            #pragma unroll
            for (int nt = 0; nt < 4; nt++)
                acc[mt][nt] = __builtin_amdgcn_mfma_f32_16x16x32_bf16(
                    af[mt], bfr[nt], acc[mt][nt], 0, 0, 0);
    }

    // epilogue: C/D layout col = lane&15, row = quad*4 + reg
    float* Cs = Cm + (size_t)blockIdx.z * NPAD * NPAD;
    #pragma unroll
    for (int mt = 0; mt < 4; mt++) {
        #pragma unroll
        for (int nt = 0; nt < 4; nt++) {
            const int col = n0 + wn + nt * 16 + lr;
            const int rb  = m0 + wm + mt * 16 + quad * 4;
            #pragma unroll
            for (int r = 0; r < 4; r++)
                Cs[(size_t)(rb + r) * NPAD + col] = acc[mt][nt][r];
        }
    }
}

// ---------------------------------------------------------------------------
// Kernel 4: reduce split-K slabs + bias + relu, then FC2. One block per row.
__global__ __launch_bounds__(256) void fc2_kernel(
    const float* __restrict__ h1, const float* __restrict__ b1,
    const float* __restrict__ w2, const float* __restrict__ b2,
    float* __restrict__ out, int nslab)
{
    const int b = blockIdx.x;
    const int tid = threadIdx.x;
    float acc[NCLS];
    #pragma unroll
    for (int o = 0; o < NCLS; o++) acc[o] = 0.f;
    for (int n = tid; n < NFC1; n += 256) {
        float hv = b1[n];
        for (int s = 0; s < nslab; s++)
            hv += h1[(size_t)s * NPAD * NPAD + (size_t)b * NPAD + n];
        float h = fmaxf(hv, 0.f);
        #pragma unroll
        for (int o = 0; o < NCLS; o++)
            acc[o] = fmaf(h, w2[o * NFC1 + n], acc[o]);
    }
    __shared__ float red[4][NCLS];
    #pragma unroll
    for (int o = 0; o < NCLS; o++) {
        float v = acc[o];
        #pragma unroll
        for (int s = 32; s > 0; s >>= 1) v += __shfl_down(v, s);
        if ((tid & 63) == 0) red[tid >> 6][o] = v;
    }
    __syncthreads();
    if (tid < NCLS)
        out[b * NCLS + tid] = red[0][tid] + red[1][tid] + red[2][tid] +
                              red[3][tid] + b2[tid];
}

// ---------------------------------------------------------------------------
extern "C" void kernel_launch(void* const* d_in, const int* in_sizes, int n_in,
                              void* d_out, int out_size, void* d_ws, size_t ws_size,
                              hipStream_t stream)
{
    (void)n_in; (void)out_size;
    const float* x     = (const float*)d_in[0];
    const float* w_hs  = (const float*)d_in[1];
    const float* b_hs  = (const float*)d_in[2];
    const float* w_ls  = (const float*)d_in[3];
    const float* b_ls  = (const float*)d_in[4];
    const float* w_hi1 = (const float*)d_in[5];
    const float* b_hi1 = (const float*)d_in[6];
    const float* w_hi2 = (const float*)d_in[7];
    const float* b_hi2 = (const float*)d_in[8];
    const float* w_li1 = (const float*)d_in[9];
    const float* b_li1 = (const float*)d_in[10];
    const float* w_li2 = (const float*)d_in[11];
    const float* b_li2 = (const float*)d_in[12];
    const float* w_fc1 = (const float*)d_in[13];
    const float* b_fc1 = (const float*)d_in[14];
    const float* w_fc2 = (const float*)d_in[15];
    const float* b_fc2 = (const float*)d_in[16];
    float* out = (float*)d_out;

    const int B = in_sizes[0] / (T_LEN * C_CH);    // 2048

    char* ws = (char*)d_ws;
    __hip_bfloat16* feat = (__hip_bfloat16*)ws;                 // B*KPAD*2
    __hip_bfloat16* wb = (__hip_bfloat16*)(ws + (size_t)B * KPAD * 2);
    float* h1 = (float*)(ws + (size_t)B * KPAD * 2 + (size_t)NPAD * KPAD * 2);

    const size_t base = (size_t)B * KPAD * 2 + (size_t)NPAD * KPAD * 2;
    const size_t need4 = base + (size_t)4 * NPAD * NPAD * 4;
    const int sk = (ws_size >= need4) ? 4 : 2;     // split-K slabs that fit

    pad_w_kernel<<<dim3((NPAD * 896) / 256), 256, 0, stream>>>(w_fc1, wb);
    feat_kernel<<<dim3(B), 256, 0, stream>>>(
        x, w_hs, b_hs, w_ls, b_ls, w_hi1, b_hi1, w_hi2, b_hi2,
        w_li1, b_li1, w_li2, b_li2, feat);
    gemm_kernel<<<dim3(NPAD / 128, B / 128, sk), 256, 0, stream>>>(
        feat, wb, h1, KPAD / sk);
    fc2_kernel<<<dim3(B), 256, 0, stream>>>(h1, b_fc1, w_fc2, b_fc2, out, sk);
}

// Round 4
// 521.837 us; speedup vs baseline: 1.2128x; 1.2128x over previous
//
#include <hip/hip_runtime.h>
#include <hip/hip_bf16.h>

#define T_LEN 96
#define C_CH  66
#define FIN   7128   // 9*66*12
#define KPAD  7168   // 224*32
#define NFC1  1936
#define NPAD  2048
#define NCLS  14

typedef __bf16 bf16x8 __attribute__((ext_vector_type(8)));
typedef float  f32x4  __attribute__((ext_vector_type(4)));

#define GLD_LDS(gp, lp) __builtin_amdgcn_global_load_lds(                     \
    (__attribute__((address_space(1))) void*)(gp),                            \
    (__attribute__((address_space(3))) void*)(lp), 16, 0, 0)

// ---------------------------------------------------------------------------
// Kernel 1: w_fc1 (1936 x 7128 fp32) -> bf16 (2048 x 7168), zero padded.
__global__ __launch_bounds__(256) void pad_w_kernel(
    const float* __restrict__ w, __hip_bfloat16* __restrict__ wb)
{
    int idx = blockIdx.x * 256 + threadIdx.x;     // chunk id, total 2048*896
    int row = idx / 896;
    int cc  = idx - row * 896;                    // 896 chunks of 8 per row
    float4 a = {0.f, 0.f, 0.f, 0.f}, b = {0.f, 0.f, 0.f, 0.f};
    if (row < NFC1 && cc < 891) {                 // 891*8 = 7128
        const float4* src = (const float4*)(w + (size_t)row * FIN + cc * 8);
        a = src[0];
        b = src[1];
    }
    __align__(16) __hip_bfloat16 v[8];
    v[0] = __float2bfloat16(a.x); v[1] = __float2bfloat16(a.y);
    v[2] = __float2bfloat16(a.z); v[3] = __float2bfloat16(a.w);
    v[4] = __float2bfloat16(b.x); v[5] = __float2bfloat16(b.y);
    v[6] = __float2bfloat16(b.z); v[7] = __float2bfloat16(b.w);
    *(int4*)(wb + (size_t)row * KPAD + cc * 8) = *(const int4*)v;
}

// ---------------------------------------------------------------------------
// Kernel 2a/2b: conv branch, fully register-resident per-lane pipeline.
// One lane = one (b, c); block = 1 wave of 64 batches; grid (B/64, C).
// All weights wave-uniform (scalar loads); no LDS, no barriers, no shuffles.
// DO_EXTRA: also emit orig (pool2^3 of x) and zero the K-pad tail.
template <int K, bool DO_EXTRA>
__global__ __launch_bounds__(64) void conv_kernel(
    const float* __restrict__ x,
    const float* __restrict__ wS, const float* __restrict__ bS,
    const float* __restrict__ wI1, const float* __restrict__ bI1,
    const float* __restrict__ wI2, const float* __restrict__ bI2,
    __hip_bfloat16* __restrict__ feat, int out_off)
{
    constexpr int PAD = K / 2;
    const int lane = threadIdx.x;
    const int b = blockIdx.x * 64 + lane;
    const int c = blockIdx.y;

    const float* wi1 = wI1 + c * (4 * 8 * K);
    const float* bi1 = bI1 + c * 4;
    const float* wi2 = wI2 + c * (4 * 4 * K);
    const float* bi2 = bI2 + c * 4;

    // gather this lane's channel series (+ zero halos)
    float xh[T_LEN + 2 * PAD];
    #pragma unroll
    for (int i = 0; i < PAD; i++) { xh[i] = 0.f; xh[T_LEN + PAD + i] = 0.f; }
    const float* xb = x + (size_t)b * (T_LEN * C_CH) + c;
    #pragma unroll
    for (int t = 0; t < T_LEN; t++) xh[PAD + t] = xb[(size_t)t * C_CH];

    __hip_bfloat16* frow = feat + (size_t)b * KPAD + c * 108;

    if (DO_EXTRA) {
        // orig = pool2^3 = mean of 8 consecutive
        #pragma unroll
        for (int q = 0; q < 12; q++) {
            float s = 0.f;
            #pragma unroll
            for (int k = 0; k < 8; k++) s += xh[PAD + q * 8 + k];
            frow[q] = __float2bfloat16(s * 0.125f);
        }
        // zero this row's K padding (once total: only the c==0 blocks)
        if (c == 0) {
            __hip_bfloat16* tail = feat + (size_t)b * KPAD + FIN;
            #pragma unroll
            for (int i = 0; i < (KPAD - FIN); i++)
                tail[i] = __float2bfloat16(0.f);
        }
    }

    // stage 1 (shared conv 1->8) fused with stage 2 (grouped 8->4) pre-acts
    float s2a[4 * 48];
    #pragma unroll
    for (int oc = 0; oc < 4; oc++) {
        const float bv = bi1[oc];
        #pragma unroll
        for (int p = 0; p < 48; p++) s2a[oc * 48 + p] = bv;
    }

    #pragma unroll 1
    for (int ic = 0; ic < 8; ic++) {
        float ws[K];
        #pragma unroll
        for (int k = 0; k < K; k++) ws[k] = wS[ic * K + k];
        const float bs = bS[ic];

        float th[48 + 2 * PAD];          // stage-1 pooled row (+halo)
        #pragma unroll
        for (int i = 0; i < PAD; i++) { th[i] = 0.f; th[48 + PAD + i] = 0.f; }
        #pragma unroll
        for (int p = 0; p < 48; p++) {
            float y0 = bs, y1 = bs;
            #pragma unroll
            for (int k = 0; k < K; k++) {
                y0 = fmaf(ws[k], xh[2 * p + k], y0);
                y1 = fmaf(ws[k], xh[2 * p + 1 + k], y1);
            }
            th[PAD + p] = 0.5f * (fmaxf(y0, 0.f) + fmaxf(y1, 0.f));
        }

        float wv0[K], wv1[K], wv2[K], wv3[K];
        #pragma unroll
        for (int k = 0; k < K; k++) {
            wv0[k] = wi1[(0 * 8 + ic) * K + k];
            wv1[k] = wi1[(1 * 8 + ic) * K + k];
            wv2[k] = wi1[(2 * 8 + ic) * K + k];
            wv3[k] = wi1[(3 * 8 + ic) * K + k];
        }
        #pragma unroll
        for (int p = 0; p < 48; p++) {
            float a0 = s2a[0 * 48 + p], a1 = s2a[1 * 48 + p];
            float a2 = s2a[2 * 48 + p], a3 = s2a[3 * 48 + p];
            #pragma unroll
            for (int k = 0; k < K; k++) {
                const float t = th[p + k];
                a0 = fmaf(wv0[k], t, a0);
                a1 = fmaf(wv1[k], t, a1);
                a2 = fmaf(wv2[k], t, a2);
                a3 = fmaf(wv3[k], t, a3);
            }
            s2a[0 * 48 + p] = a0; s2a[1 * 48 + p] = a1;
            s2a[2 * 48 + p] = a2; s2a[3 * 48 + p] = a3;
        }
    }

    // pool stage 2 -> s2ph[4][24] (+halo)
    float s2ph[4][24 + 2 * PAD];
    #pragma unroll
    for (int ic = 0; ic < 4; ic++) {
        #pragma unroll
        for (int i = 0; i < PAD; i++) {
            s2ph[ic][i] = 0.f; s2ph[ic][24 + PAD + i] = 0.f;
        }
        #pragma unroll
        for (int q = 0; q < 24; q++)
            s2ph[ic][PAD + q] = 0.5f * (fmaxf(s2a[ic * 48 + 2 * q], 0.f) +
                                        fmaxf(s2a[ic * 48 + 2 * q + 1], 0.f));
    }

    // stage 3 (grouped 4->4) + relu + pool2 -> out[4][12] bf16
    #pragma unroll 1
    for (int oc = 0; oc < 4; oc++) {
        const float bv = bi2[oc];
        #pragma unroll
        for (int q = 0; q < 12; q++) {
            float y0 = bv, y1 = bv;
            #pragma unroll
            for (int ic = 0; ic < 4; ic++) {
                #pragma unroll
                for (int k = 0; k < K; k++) {
                    const float w = wi2[(oc * 4 + ic) * K + k];
                    y0 = fmaf(w, s2ph[ic][2 * q + k], y0);
                    y1 = fmaf(w, s2ph[ic][2 * q + 1 + k], y1);
                }
            }
            frow[out_off + oc * 12 + q] =
                __float2bfloat16(0.5f * (fmaxf(y0, 0.f) + fmaxf(y1, 0.f)));
        }
    }
}

// ---------------------------------------------------------------------------
// Kernel 3: FC1 GEMM, A(2048xKPAD bf16) * W(2048xKPAD bf16)^T, split-K,
// plain fp32 stores into slabs (no atomics); bias/relu/reduce in fc2.
__global__ __launch_bounds__(256) void gemm_kernel(
    const __hip_bfloat16* __restrict__ A,
    const __hip_bfloat16* __restrict__ Bw,
    float* __restrict__ Cm, int kchunk)
{
    __shared__ __align__(16) __hip_bfloat16 As[4096];  // 128 x 32
    __shared__ __align__(16) __hip_bfloat16 Bs[4096];  // 128 x 32

    const int tid  = threadIdx.x;
    const int lane = tid & 63;
    const int wid  = tid >> 6;
    const int m0 = blockIdx.y * 128;
    const int n0 = blockIdx.x * 128;
    const int wm = (wid >> 1) * 64;
    const int wn = (wid & 1) * 64;
    const int lr = lane & 15;
    const int quad = lane >> 4;

    const int r0 = tid >> 2, c0 = (tid & 3) * 8;
    const __hip_bfloat16* gA0 = A  + (size_t)(m0 + r0) * KPAD + c0;
    const __hip_bfloat16* gA1 = gA0 + (size_t)64 * KPAD;
    const __hip_bfloat16* gB0 = Bw + (size_t)(n0 + r0) * KPAD + c0;
    const __hip_bfloat16* gB1 = gB0 + (size_t)64 * KPAD;
    __hip_bfloat16* lA0 = As + wid * 512;
    __hip_bfloat16* lA1 = As + 2048 + wid * 512;
    __hip_bfloat16* lB0 = Bs + wid * 512;
    __hip_bfloat16* lB1 = Bs + 2048 + wid * 512;

    f32x4 acc[4][4] = {};

    const int kBeg = blockIdx.z * kchunk;
    const int kEnd = kBeg + kchunk;
    for (int k0 = kBeg; k0 < kEnd; k0 += 32) {
        __syncthreads();
        GLD_LDS(gA0 + k0, lA0);
        GLD_LDS(gA1 + k0, lA1);
        GLD_LDS(gB0 + k0, lB0);
        GLD_LDS(gB1 + k0, lB1);
        __syncthreads();
        bf16x8 af[4], bfr[4];
        #pragma unroll
        for (int mt = 0; mt < 4; mt++)
            af[mt] = *(const bf16x8*)(As + (wm + mt * 16 + lr) * 32 + quad * 8);
        #pragma unroll
        for (int nt = 0; nt < 4; nt++)
            bfr[nt] = *(const bf16x8*)(Bs + (wn + nt * 16 + lr) * 32 + quad * 8);
        #pragma unroll
        for (int mt = 0; mt < 4; mt++)
            #pragma unroll
            for (int nt = 0; nt < 4; nt++)
                acc[mt][nt] = __builtin_amdgcn_mfma_f32_16x16x32_bf16(
                    af[mt], bfr[nt], acc[mt][nt], 0, 0, 0);
    }

    // epilogue: C/D layout col = lane&15, row = quad*4 + reg
    float* Cs = Cm + (size_t)blockIdx.z * NPAD * NPAD;
    #pragma unroll
    for (int mt = 0; mt < 4; mt++) {
        #pragma unroll
        for (int nt = 0; nt < 4; nt++) {
            const int col = n0 + wn + nt * 16 + lr;
            const int rb  = m0 + wm + mt * 16 + quad * 4;
            #pragma unroll
            for (int r = 0; r < 4; r++)
                Cs[(size_t)(rb + r) * NPAD + col] = acc[mt][nt][r];
        }
    }
}

// ---------------------------------------------------------------------------
// Kernel 4: reduce split-K slabs + bias + relu, then FC2. One block per row.
__global__ __launch_bounds__(256) void fc2_kernel(
    const float* __restrict__ h1, const float* __restrict__ b1,
    const float* __restrict__ w2, const float* __restrict__ b2,
    float* __restrict__ out, int nslab)
{
    const int b = blockIdx.x;
    const int tid = threadIdx.x;
    float acc[NCLS];
    #pragma unroll
    for (int o = 0; o < NCLS; o++) acc[o] = 0.f;
    for (int n = tid; n < NFC1; n += 256) {
        float hv = b1[n];
        for (int s = 0; s < nslab; s++)
            hv += h1[(size_t)s * NPAD * NPAD + (size_t)b * NPAD + n];
        float h = fmaxf(hv, 0.f);
        #pragma unroll
        for (int o = 0; o < NCLS; o++)
            acc[o] = fmaf(h, w2[o * NFC1 + n], acc[o]);
    }
    __shared__ float red[4][NCLS];
    #pragma unroll
    for (int o = 0; o < NCLS; o++) {
        float v = acc[o];
        #pragma unroll
        for (int s = 32; s > 0; s >>= 1) v += __shfl_down(v, s);
        if ((tid & 63) == 0) red[tid >> 6][o] = v;
    }
    __syncthreads();
    if (tid < NCLS)
        out[b * NCLS + tid] = red[0][tid] + red[1][tid] + red[2][tid] +
                              red[3][tid] + b2[tid];
}

// ---------------------------------------------------------------------------
extern "C" void kernel_launch(void* const* d_in, const int* in_sizes, int n_in,
                              void* d_out, int out_size, void* d_ws, size_t ws_size,
                              hipStream_t stream)
{
    (void)n_in; (void)out_size;
    const float* x     = (const float*)d_in[0];
    const float* w_hs  = (const float*)d_in[1];
    const float* b_hs  = (const float*)d_in[2];
    const float* w_ls  = (const float*)d_in[3];
    const float* b_ls  = (const float*)d_in[4];
    const float* w_hi1 = (const float*)d_in[5];
    const float* b_hi1 = (const float*)d_in[6];
    const float* w_hi2 = (const float*)d_in[7];
    const float* b_hi2 = (const float*)d_in[8];
    const float* w_li1 = (const float*)d_in[9];
    const float* b_li1 = (const float*)d_in[10];
    const float* w_li2 = (const float*)d_in[11];
    const float* b_li2 = (const float*)d_in[12];
    const float* w_fc1 = (const float*)d_in[13];
    const float* b_fc1 = (const float*)d_in[14];
    const float* w_fc2 = (const float*)d_in[15];
    const float* b_fc2 = (const float*)d_in[16];
    float* out = (float*)d_out;

    const int B = in_sizes[0] / (T_LEN * C_CH);    // 2048

    char* ws = (char*)d_ws;
    __hip_bfloat16* feat = (__hip_bfloat16*)ws;                 // B*KPAD*2
    __hip_bfloat16* wb = (__hip_bfloat16*)(ws + (size_t)B * KPAD * 2);
    float* h1 = (float*)(ws + (size_t)B * KPAD * 2 + (size_t)NPAD * KPAD * 2);

    const size_t base = (size_t)B * KPAD * 2 + (size_t)NPAD * KPAD * 2;
    const size_t need4 = base + (size_t)4 * NPAD * NPAD * 4;
    const int sk = (ws_size >= need4) ? 4 : 2;     // split-K slabs that fit

    pad_w_kernel<<<dim3((NPAD * 896) / 256), 256, 0, stream>>>(w_fc1, wb);
    // high branch (K=7) -> cols 60..107; low (K=3) -> cols 12..59 + orig/pad
    conv_kernel<7, false><<<dim3(B / 64, C_CH), 64, 0, stream>>>(
        x, w_hs, b_hs, w_hi1, b_hi1, w_hi2, b_hi2, feat, 60);
    conv_kernel<3, true><<<dim3(B / 64, C_CH), 64, 0, stream>>>(
        x, w_ls, b_ls, w_li1, b_li1, w_li2, b_li2, feat, 12);
    gemm_kernel<<<dim3(NPAD / 128, B / 128, sk), 256, 0, stream>>>(
        feat, wb, h1, KPAD / sk);
    fc2_kernel<<<dim3(B), 256, 0, stream>>>(h1, b_fc1, w_fc2, b_fc2, out, sk);
}

// Round 5
// 472.095 us; speedup vs baseline: 1.3406x; 1.1054x over previous
//
#include <hip/hip_runtime.h>
#include <hip/hip_bf16.h>

#define T_LEN 96
#define C_CH  66
#define FIN   7128   // 9*66*12
#define KPAD  7168   // 224*32
#define NFC1  1936
#define NPAD  2048
#define NCLS  14

typedef __bf16 bf16x8 __attribute__((ext_vector_type(8)));
typedef float  f32x4  __attribute__((ext_vector_type(4)));

#define GLD_LDS(gp, lp) __builtin_amdgcn_global_load_lds(                     \
    (__attribute__((address_space(1))) void*)(gp),                            \
    (__attribute__((address_space(3))) void*)(lp), 16, 0, 0)

// ---------------------------------------------------------------------------
// Kernel 0: transpose x (B, T*C) -> xT (T*C, B) so conv lanes (lane=b) read
// coalesced. 64x64 LDS tile, +1 pad.
__global__ __launch_bounds__(256) void transpose_kernel(
    const float* __restrict__ x, float* __restrict__ xT, int B)
{
    __shared__ float tile[64][65];
    const int t = threadIdx.x & 63;
    const int w = threadIdx.x >> 6;
    const int tc0 = blockIdx.x * 64;     // 6336 / 64 = 99
    const int b0  = blockIdx.y * 64;     // B / 64
    #pragma unroll
    for (int j = 0; j < 16; j++) {
        const int r = w * 16 + j;
        tile[r][t] = x[(size_t)(b0 + r) * (T_LEN * C_CH) + tc0 + t];
    }
    __syncthreads();
    #pragma unroll
    for (int j = 0; j < 16; j++) {
        const int r = w * 16 + j;
        xT[(size_t)(tc0 + r) * B + b0 + t] = tile[t][r];
    }
}

// ---------------------------------------------------------------------------
// Kernel 1: w_fc1 (1936 x 7128 fp32) -> bf16 (2048 x 7168), zero padded.
__global__ __launch_bounds__(256) void pad_w_kernel(
    const float* __restrict__ w, __hip_bfloat16* __restrict__ wb)
{
    int idx = blockIdx.x * 256 + threadIdx.x;     // chunk id, total 2048*896
    int row = idx / 896;
    int cc  = idx - row * 896;                    // 896 chunks of 8 per row
    float4 a = {0.f, 0.f, 0.f, 0.f}, b = {0.f, 0.f, 0.f, 0.f};
    if (row < NFC1 && cc < 891) {                 // 891*8 = 7128
        const float4* src = (const float4*)(w + (size_t)row * FIN + cc * 8);
        a = src[0];
        b = src[1];
    }
    __align__(16) __hip_bfloat16 v[8];
    v[0] = __float2bfloat16(a.x); v[1] = __float2bfloat16(a.y);
    v[2] = __float2bfloat16(a.z); v[3] = __float2bfloat16(a.w);
    v[4] = __float2bfloat16(b.x); v[5] = __float2bfloat16(b.y);
    v[6] = __float2bfloat16(b.z); v[7] = __float2bfloat16(b.w);
    *(int4*)(wb + (size_t)row * KPAD + cc * 8) = *(const int4*)v;
}

// ---------------------------------------------------------------------------
// Kernel 2a/2b: conv branch, fully register-resident per-lane pipeline.
// One lane = one (b, c); block = 1 wave; grid (B/64, C).
// __launch_bounds__(64,1): 512-VGPR budget -> NO scratch spill (live peak
// ~380). Weights wave-uniform (s_loads); no LDS, no barriers, no shuffles.
// x addressing generic: addr = b*bs + c*cs + t*ts  (supports transposed).
template <int K, bool DO_EXTRA>
__global__ __launch_bounds__(64, 1) void conv_kernel(
    const float* __restrict__ x, int ts, int bs, int cs,
    const float* __restrict__ wS, const float* __restrict__ bS,
    const float* __restrict__ wI1, const float* __restrict__ bI1,
    const float* __restrict__ wI2, const float* __restrict__ bI2,
    __hip_bfloat16* __restrict__ feat, int out_off)
{
    constexpr int PAD = K / 2;
    const int lane = threadIdx.x;
    const int b = blockIdx.x * 64 + lane;
    const int c = blockIdx.y;

    const float* wi1 = wI1 + c * (4 * 8 * K);
    const float* bi1 = bI1 + c * 4;
    const float* wi2 = wI2 + c * (4 * 4 * K);
    const float* bi2 = bI2 + c * 4;

    // gather this lane's channel series (+ zero halos); coalesced if ts-major
    float xh[T_LEN + 2 * PAD];
    #pragma unroll
    for (int i = 0; i < PAD; i++) { xh[i] = 0.f; xh[T_LEN + PAD + i] = 0.f; }
    const float* xb = x + (size_t)b * bs + (size_t)c * cs;
    #pragma unroll
    for (int t = 0; t < T_LEN; t++) xh[PAD + t] = xb[(size_t)t * ts];

    __hip_bfloat16* frow = feat + (size_t)b * KPAD + c * 108;

    if (DO_EXTRA) {
        // orig = pool2^3 = mean of 8 consecutive
        #pragma unroll
        for (int q = 0; q < 12; q++) {
            float s = 0.f;
            #pragma unroll
            for (int k = 0; k < 8; k++) s += xh[PAD + q * 8 + k];
            frow[q] = __float2bfloat16(s * 0.125f);
        }
        // zero this row's K padding (only the c==0 blocks); 5 x int4
        if (c == 0) {
            int4* tail = (int4*)(feat + (size_t)b * KPAD + FIN);
            const int4 z = {0, 0, 0, 0};
            #pragma unroll
            for (int i = 0; i < 5; i++) tail[i] = z;
        }
    }

    // stage 1 (shared conv 1->8) fused with stage 2 (grouped 8->4) pre-acts
    float s2a[4 * 48];
    #pragma unroll
    for (int oc = 0; oc < 4; oc++) {
        const float bv = bi1[oc];
        #pragma unroll
        for (int p = 0; p < 48; p++) s2a[oc * 48 + p] = bv;
    }

    #pragma unroll 1
    for (int ic = 0; ic < 8; ic++) {
        float ws[K];
        #pragma unroll
        for (int k = 0; k < K; k++) ws[k] = wS[ic * K + k];
        const float bs1 = bS[ic];

        float th[48 + 2 * PAD];          // stage-1 pooled row (+halo)
        #pragma unroll
        for (int i = 0; i < PAD; i++) { th[i] = 0.f; th[48 + PAD + i] = 0.f; }
        #pragma unroll
        for (int p = 0; p < 48; p++) {
            float y0 = bs1, y1 = bs1;
            #pragma unroll
            for (int k = 0; k < K; k++) {
                y0 = fmaf(ws[k], xh[2 * p + k], y0);
                y1 = fmaf(ws[k], xh[2 * p + 1 + k], y1);
            }
            th[PAD + p] = 0.5f * (fmaxf(y0, 0.f) + fmaxf(y1, 0.f));
        }

        float wv0[K], wv1[K], wv2[K], wv3[K];
        #pragma unroll
        for (int k = 0; k < K; k++) {
            wv0[k] = wi1[(0 * 8 + ic) * K + k];
            wv1[k] = wi1[(1 * 8 + ic) * K + k];
            wv2[k] = wi1[(2 * 8 + ic) * K + k];
            wv3[k] = wi1[(3 * 8 + ic) * K + k];
        }
        #pragma unroll
        for (int p = 0; p < 48; p++) {
            float a0 = s2a[0 * 48 + p], a1 = s2a[1 * 48 + p];
            float a2 = s2a[2 * 48 + p], a3 = s2a[3 * 48 + p];
            #pragma unroll
            for (int k = 0; k < K; k++) {
                const float t = th[p + k];
                a0 = fmaf(wv0[k], t, a0);
                a1 = fmaf(wv1[k], t, a1);
                a2 = fmaf(wv2[k], t, a2);
                a3 = fmaf(wv3[k], t, a3);
            }
            s2a[0 * 48 + p] = a0; s2a[1 * 48 + p] = a1;
            s2a[2 * 48 + p] = a2; s2a[3 * 48 + p] = a3;
        }
    }

    // pool stage 2 -> s2ph[4][24] (+halo)
    float s2ph[4][24 + 2 * PAD];
    #pragma unroll
    for (int ic = 0; ic < 4; ic++) {
        #pragma unroll
        for (int i = 0; i < PAD; i++) {
            s2ph[ic][i] = 0.f; s2ph[ic][24 + PAD + i] = 0.f;
        }
        #pragma unroll
        for (int q = 0; q < 24; q++)
            s2ph[ic][PAD + q] = 0.5f * (fmaxf(s2a[ic * 48 + 2 * q], 0.f) +
                                        fmaxf(s2a[ic * 48 + 2 * q + 1], 0.f));
    }

    // stage 3 (grouped 4->4) + relu + pool2 -> out[4][12] bf16
    #pragma unroll 1
    for (int oc = 0; oc < 4; oc++) {
        const float bv = bi2[oc];
        #pragma unroll
        for (int q = 0; q < 12; q++) {
            float y0 = bv, y1 = bv;
            #pragma unroll
            for (int ic = 0; ic < 4; ic++) {
                #pragma unroll
                for (int k = 0; k < K; k++) {
                    const float w = wi2[(oc * 4 + ic) * K + k];
                    y0 = fmaf(w, s2ph[ic][2 * q + k], y0);
                    y1 = fmaf(w, s2ph[ic][2 * q + 1 + k], y1);
                }
            }
            frow[out_off + oc * 12 + q] =
                __float2bfloat16(0.5f * (fmaxf(y0, 0.f) + fmaxf(y1, 0.f)));
        }
    }
}

// ---------------------------------------------------------------------------
// Kernel 3: FC1 GEMM, A(2048xKPAD bf16) * W(2048xKPAD bf16)^T, split-K,
// plain fp32 stores into slabs (no atomics); bias/relu/reduce in fc2.
__global__ __launch_bounds__(256) void gemm_kernel(
    const __hip_bfloat16* __restrict__ A,
    const __hip_bfloat16* __restrict__ Bw,
    float* __restrict__ Cm, int kchunk)
{
    __shared__ __align__(16) __hip_bfloat16 As[4096];  // 128 x 32
    __shared__ __align__(16) __hip_bfloat16 Bs[4096];  // 128 x 32

    const int tid  = threadIdx.x;
    const int lane = tid & 63;
    const int wid  = tid >> 6;
    const int m0 = blockIdx.y * 128;
    const int n0 = blockIdx.x * 128;
    const int wm = (wid >> 1) * 64;
    const int wn = (wid & 1) * 64;
    const int lr = lane & 15;
    const int quad = lane >> 4;

    const int r0 = tid >> 2, c0 = (tid & 3) * 8;
    const __hip_bfloat16* gA0 = A  + (size_t)(m0 + r0) * KPAD + c0;
    const __hip_bfloat16* gA1 = gA0 + (size_t)64 * KPAD;
    const __hip_bfloat16* gB0 = Bw + (size_t)(n0 + r0) * KPAD + c0;
    const __hip_bfloat16* gB1 = gB0 + (size_t)64 * KPAD;
    __hip_bfloat16* lA0 = As + wid * 512;
    __hip_bfloat16* lA1 = As + 2048 + wid * 512;
    __hip_bfloat16* lB0 = Bs + wid * 512;
    __hip_bfloat16* lB1 = Bs + 2048 + wid * 512;

    f32x4 acc[4][4] = {};

    const int kBeg = blockIdx.z * kchunk;
    const int kEnd = kBeg + kchunk;
    for (int k0 = kBeg; k0 < kEnd; k0 += 32) {
        __syncthreads();
        GLD_LDS(gA0 + k0, lA0);
        GLD_LDS(gA1 + k0, lA1);
        GLD_LDS(gB0 + k0, lB0);
        GLD_LDS(gB1 + k0, lB1);
        __syncthreads();
        bf16x8 af[4], bfr[4];
        #pragma unroll
        for (int mt = 0; mt < 4; mt++)
            af[mt] = *(const bf16x8*)(As + (wm + mt * 16 + lr) * 32 + quad * 8);
        #pragma unroll
        for (int nt = 0; nt < 4; nt++)
            bfr[nt] = *(const bf16x8*)(Bs + (wn + nt * 16 + lr) * 32 + quad * 8);
        #pragma unroll
        for (int mt = 0; mt < 4; mt++)
            #pragma unroll
            for (int nt = 0; nt < 4; nt++)
                acc[mt][nt] = __builtin_amdgcn_mfma_f32_16x16x32_bf16(
                    af[mt], bfr[nt], acc[mt][nt], 0, 0, 0);
    }

    // epilogue: C/D layout col = lane&15, row = quad*4 + reg
    float* Cs = Cm + (size_t)blockIdx.z * NPAD * NPAD;
    #pragma unroll
    for (int mt = 0; mt < 4; mt++) {
        #pragma unroll
        for (int nt = 0; nt < 4; nt++) {
            const int col = n0 + wn + nt * 16 + lr;
            const int rb  = m0 + wm + mt * 16 + quad * 4;
            #pragma unroll
            for (int r = 0; r < 4; r++)
                Cs[(size_t)(rb + r) * NPAD + col] = acc[mt][nt][r];
        }
    }
}

// ---------------------------------------------------------------------------
// Kernel 4: reduce split-K slabs + bias + relu, then FC2. One block per row.
__global__ __launch_bounds__(256) void fc2_kernel(
    const float* __restrict__ h1, const float* __restrict__ b1,
    const float* __restrict__ w2, const float* __restrict__ b2,
    float* __restrict__ out, int nslab)
{
    const int b = blockIdx.x;
    const int tid = threadIdx.x;
    float acc[NCLS];
    #pragma unroll
    for (int o = 0; o < NCLS; o++) acc[o] = 0.f;
    for (int n = tid; n < NFC1; n += 256) {
        float hv = b1[n];
        for (int s = 0; s < nslab; s++)
            hv += h1[(size_t)s * NPAD * NPAD + (size_t)b * NPAD + n];
        float h = fmaxf(hv, 0.f);
        #pragma unroll
        for (int o = 0; o < NCLS; o++)
            acc[o] = fmaf(h, w2[o * NFC1 + n], acc[o]);
    }
    __shared__ float red[4][NCLS];
    #pragma unroll
    for (int o = 0; o < NCLS; o++) {
        float v = acc[o];
        #pragma unroll
        for (int s = 32; s > 0; s >>= 1) v += __shfl_down(v, s);
        if ((tid & 63) == 0) red[tid >> 6][o] = v;
    }
    __syncthreads();
    if (tid < NCLS)
        out[b * NCLS + tid] = red[0][tid] + red[1][tid] + red[2][tid] +
                              red[3][tid] + b2[tid];
}

// ---------------------------------------------------------------------------
extern "C" void kernel_launch(void* const* d_in, const int* in_sizes, int n_in,
                              void* d_out, int out_size, void* d_ws, size_t ws_size,
                              hipStream_t stream)
{
    (void)n_in; (void)out_size;
    const float* x     = (const float*)d_in[0];
    const float* w_hs  = (const float*)d_in[1];
    const float* b_hs  = (const float*)d_in[2];
    const float* w_ls  = (const float*)d_in[3];
    const float* b_ls  = (const float*)d_in[4];
    const float* w_hi1 = (const float*)d_in[5];
    const float* b_hi1 = (const float*)d_in[6];
    const float* w_hi2 = (const float*)d_in[7];
    const float* b_hi2 = (const float*)d_in[8];
    const float* w_li1 = (const float*)d_in[9];
    const float* b_li1 = (const float*)d_in[10];
    const float* w_li2 = (const float*)d_in[11];
    const float* b_li2 = (const float*)d_in[12];
    const float* w_fc1 = (const float*)d_in[13];
    const float* b_fc1 = (const float*)d_in[14];
    const float* w_fc2 = (const float*)d_in[15];
    const float* b_fc2 = (const float*)d_in[16];
    float* out = (float*)d_out;

    const int B = in_sizes[0] / (T_LEN * C_CH);    // 2048

    char* ws = (char*)d_ws;
    const size_t featB = (size_t)B * KPAD * 2;         // 29.4 MB
    const size_t wbB   = (size_t)NPAD * KPAD * 2;      // 29.4 MB
    const size_t slabB = (size_t)NPAD * NPAD * 4;      // 16.8 MB
    const size_t xtB   = (size_t)T_LEN * C_CH * B * 4; // 51.9 MB
    const size_t base2 = featB + wbB;

    __hip_bfloat16* feat = (__hip_bfloat16*)ws;
    __hip_bfloat16* wb   = (__hip_bfloat16*)(ws + featB);
    float* h1            = (float*)(ws + base2);

    const int sk = (ws_size >= base2 + 4 * slabB) ? 4 : 2;
    const bool use_xt = (ws_size >= base2 + sk * slabB + xtB);
    float* xT = (float*)(ws + base2 + sk * slabB);

    pad_w_kernel<<<dim3((NPAD * 896) / 256), 256, 0, stream>>>(w_fc1, wb);

    const float* cx = x;
    int ts = C_CH, bsi = T_LEN * C_CH, cs = 1;
    if (use_xt) {
        transpose_kernel<<<dim3(99, B / 64), 256, 0, stream>>>(x, xT, B);
        cx = xT; ts = C_CH * B; bsi = 1; cs = B;
    }
    // high branch (K=7) -> cols 60..107; low (K=3) -> cols 12..59 + orig/pad
    conv_kernel<7, false><<<dim3(B / 64, C_CH), 64, 0, stream>>>(
        cx, ts, bsi, cs, w_hs, b_hs, w_hi1, b_hi1, w_hi2, b_hi2, feat, 60);
    conv_kernel<3, true><<<dim3(B / 64, C_CH), 64, 0, stream>>>(
        cx, ts, bsi, cs, w_ls, b_ls, w_li1, b_li1, w_li2, b_li2, feat, 12);
    gemm_kernel<<<dim3(NPAD / 128, B / 128, sk), 256, 0, stream>>>(
        feat, wb, h1, KPAD / sk);
    fc2_kernel<<<dim3(B), 256, 0, stream>>>(h1, b_fc1, w_fc2, b_fc2, out, sk);
}

// Round 6
// 431.161 us; speedup vs baseline: 1.4679x; 1.0949x over previous
//
#include <hip/hip_runtime.h>
#include <hip/hip_bf16.h>

#define T_LEN 96
#define C_CH  66
#define FIN   7128   // 9*66*12
#define KPAD  7168   // 224*32
#define NFC1  1936
#define NPAD  2048
#define NCLS  14

typedef __bf16 bf16x8 __attribute__((ext_vector_type(8)));
typedef float  f32x4  __attribute__((ext_vector_type(4)));

#define GLD_LDS(gp, lp) __builtin_amdgcn_global_load_lds(                     \
    (__attribute__((address_space(1))) void*)(gp),                            \
    (__attribute__((address_space(3))) void*)(lp), 16, 0, 0)

// ---------------------------------------------------------------------------
// Kernel 0: transpose x (B, T*C) -> xT (T*C, B) so conv lanes (lane=b) read
// coalesced. 64x64 LDS tile, +1 pad.
__global__ __launch_bounds__(256) void transpose_kernel(
    const float* __restrict__ x, float* __restrict__ xT, int B)
{
    __shared__ float tile[64][65];
    const int t = threadIdx.x & 63;
    const int w = threadIdx.x >> 6;
    const int tc0 = blockIdx.x * 64;     // 6336 / 64 = 99
    const int b0  = blockIdx.y * 64;     // B / 64
    #pragma unroll
    for (int j = 0; j < 16; j++) {
        const int r = w * 16 + j;
        tile[r][t] = x[(size_t)(b0 + r) * (T_LEN * C_CH) + tc0 + t];
    }
    __syncthreads();
    #pragma unroll
    for (int j = 0; j < 16; j++) {
        const int r = w * 16 + j;
        xT[(size_t)(tc0 + r) * B + b0 + t] = tile[t][r];
    }
}

// ---------------------------------------------------------------------------
// Kernel 1: w_fc1 (1936 x 7128 fp32) -> bf16 (2048 x 7168), zero padded.
__global__ __launch_bounds__(256) void pad_w_kernel(
    const float* __restrict__ w, __hip_bfloat16* __restrict__ wb)
{
    int idx = blockIdx.x * 256 + threadIdx.x;     // chunk id, total 2048*896
    int row = idx / 896;
    int cc  = idx - row * 896;                    // 896 chunks of 8 per row
    float4 a = {0.f, 0.f, 0.f, 0.f}, b = {0.f, 0.f, 0.f, 0.f};
    if (row < NFC1 && cc < 891) {                 // 891*8 = 7128
        const float4* src = (const float4*)(w + (size_t)row * FIN + cc * 8);
        a = src[0];
        b = src[1];
    }
    __align__(16) __hip_bfloat16 v[8];
    v[0] = __float2bfloat16(a.x); v[1] = __float2bfloat16(a.y);
    v[2] = __float2bfloat16(a.z); v[3] = __float2bfloat16(a.w);
    v[4] = __float2bfloat16(b.x); v[5] = __float2bfloat16(b.y);
    v[6] = __float2bfloat16(b.z); v[7] = __float2bfloat16(b.w);
    *(int4*)(wb + (size_t)row * KPAD + cc * 8) = *(const int4*)v;
}

// ---------------------------------------------------------------------------
// Kernel 2: conv branches, per-lane pipeline TILED over positions so the
// live set stays ~200 VGPRs (no scratch spill by construction).
// Tile t covers stage-2 pre-pool positions [12t, 12t+12); x window re-read
// per tile (compile-time indices via fully-unrolled tile loop). Stage-2
// pooled output accumulates in static-index register array s2phR[4][24].
// One lane = one (b, c); grid (B/64, C, 2): z=0 high (K=7), z=1 low (K=3).
template <int K, bool DO_EXTRA>
__device__ __forceinline__ void conv_branch(
    const float* __restrict__ xb, int ts,
    const float* __restrict__ wS, const float* __restrict__ bS,
    const float* __restrict__ wi1, const float* __restrict__ bi1,
    const float* __restrict__ wi2, const float* __restrict__ bi2,
    __hip_bfloat16* __restrict__ frow, int out_off)
{
    constexpr int PAD = K / 2;
    constexpr int XW  = 24 + 6 * PAD;   // x window per tile
    constexpr int THW = 12 + 2 * PAD;   // stage-1 pooled window per tile

    float s2phR[4][24];                 // stage-2 pooled (static indices)

    #pragma unroll
    for (int tt = 0; tt < 4; tt++) {    // fully unrolled: all indices const
        // x window: global t = 24*tt - 3*PAD + i (zero outside [0,96))
        float xw[XW];
        #pragma unroll
        for (int i = 0; i < XW; i++) {
            const int t = 24 * tt - 3 * PAD + i;     // compile-time
            xw[i] = (t >= 0 && t < T_LEN) ? xb[(size_t)t * ts] : 0.f;
        }

        if (DO_EXTRA) {                 // orig = pool2^3: 3 outputs per tile
            #pragma unroll
            for (int r = 0; r < 3; r++) {
                float s = 0.f;
                #pragma unroll
                for (int k = 0; k < 8; k++) s += xw[3 * PAD + 8 * r + k];
                frow[3 * tt + r] = __float2bfloat16(s * 0.125f);
            }
        }

        float s2a[4][12];
        #pragma unroll
        for (int oc = 0; oc < 4; oc++) {
            const float bv = bi1[oc];
            #pragma unroll
            for (int q = 0; q < 12; q++) s2a[oc][q] = bv;
        }

        #pragma unroll 1
        for (int ic = 0; ic < 8; ic++) {
            const float bs1 = bS[ic];
            float thw[THW];             // stage-1 pooled window (this ic)
            #pragma unroll
            for (int j = 0; j < THW; j++) {
                const int jg = 12 * tt - PAD + j;    // compile-time
                if (jg < 0 || jg >= 48) { thw[j] = 0.f; continue; }
                float y0 = bs1, y1 = bs1;
                #pragma unroll
                for (int k = 0; k < K; k++) {
                    const float w = wS[ic * K + k];
                    y0 = fmaf(w, xw[2 * j + k], y0);
                    y1 = fmaf(w, xw[2 * j + 1 + k], y1);
                }
                thw[j] = 0.5f * (fmaxf(y0, 0.f) + fmaxf(y1, 0.f));
            }
            #pragma unroll
            for (int q = 0; q < 12; q++) {
                #pragma unroll
                for (int oc = 0; oc < 4; oc++) {
                    float a = s2a[oc][q];
                    #pragma unroll
                    for (int k = 0; k < K; k++)
                        a = fmaf(wi1[(oc * 8 + ic) * K + k], thw[q + k], a);
                    s2a[oc][q] = a;
                }
            }
        }

        // pool stage 2 -> s2phR[oc][6*tt + r]
        #pragma unroll
        for (int oc = 0; oc < 4; oc++)
            #pragma unroll
            for (int r = 0; r < 6; r++)
                s2phR[oc][6 * tt + r] =
                    0.5f * (fmaxf(s2a[oc][2 * r], 0.f) +
                            fmaxf(s2a[oc][2 * r + 1], 0.f));
    }

    // stage 3 (grouped 4->4) + relu + pool2; OOB taps statically dropped
    #pragma unroll 1
    for (int oc = 0; oc < 4; oc++) {
        const float bv = bi2[oc];
        #pragma unroll
        for (int q = 0; q < 12; q++) {
            float y0 = bv, y1 = bv;
            #pragma unroll
            for (int ic = 0; ic < 4; ic++) {
                #pragma unroll
                for (int k = 0; k < K; k++) {
                    const float w = wi2[(oc * 4 + ic) * K + k];
                    const int i0 = 2 * q + k - PAD;       // compile-time
                    const int i1 = 2 * q + 1 + k - PAD;
                    if (i0 >= 0 && i0 < 24) y0 = fmaf(w, s2phR[ic][i0], y0);
                    if (i1 >= 0 && i1 < 24) y1 = fmaf(w, s2phR[ic][i1], y1);
                }
            }
            frow[out_off + oc * 12 + q] =
                __float2bfloat16(0.5f * (fmaxf(y0, 0.f) + fmaxf(y1, 0.f)));
        }
    }
}

__global__ __launch_bounds__(64, 2) void conv_fused_kernel(
    const float* __restrict__ x, int ts, int bs, int cs,
    const float* __restrict__ w_hs, const float* __restrict__ b_hs,
    const float* __restrict__ w_ls, const float* __restrict__ b_ls,
    const float* __restrict__ w_hi1, const float* __restrict__ b_hi1,
    const float* __restrict__ w_hi2, const float* __restrict__ b_hi2,
    const float* __restrict__ w_li1, const float* __restrict__ b_li1,
    const float* __restrict__ w_li2, const float* __restrict__ b_li2,
    __hip_bfloat16* __restrict__ feat)
{
    const int lane = threadIdx.x;
    const int b = blockIdx.x * 64 + lane;
    const int c = blockIdx.y;
    const float* xb = x + (size_t)b * bs + (size_t)c * cs;
    __hip_bfloat16* frow = feat + (size_t)b * KPAD + c * 108;

    if (blockIdx.z == 0) {
        conv_branch<7, false>(xb, ts, w_hs, b_hs,
                              w_hi1 + c * 224, b_hi1 + c * 4,
                              w_hi2 + c * 112, b_hi2 + c * 4, frow, 60);
    } else {
        if (c == 0) {                   // zero K-pad tail once per row
            int4* tail = (int4*)(feat + (size_t)b * KPAD + FIN);
            const int4 z = {0, 0, 0, 0};
            #pragma unroll
            for (int i = 0; i < 5; i++) tail[i] = z;
        }
        conv_branch<3, true>(xb, ts, w_ls, b_ls,
                             w_li1 + c * 96, b_li1 + c * 4,
                             w_li2 + c * 48, b_li2 + c * 4, frow, 12);
    }
}

// ---------------------------------------------------------------------------
// Kernel 3: FC1 GEMM, A(2048xKPAD bf16) * W(2048xKPAD bf16)^T, split-K,
// plain fp32 stores into slabs (no atomics); bias/relu/reduce in fc2.
__global__ __launch_bounds__(256) void gemm_kernel(
    const __hip_bfloat16* __restrict__ A,
    const __hip_bfloat16* __restrict__ Bw,
    float* __restrict__ Cm, int kchunk)
{
    __shared__ __align__(16) __hip_bfloat16 As[4096];  // 128 x 32
    __shared__ __align__(16) __hip_bfloat16 Bs[4096];  // 128 x 32

    const int tid  = threadIdx.x;
    const int lane = tid & 63;
    const int wid  = tid >> 6;
    const int m0 = blockIdx.y * 128;
    const int n0 = blockIdx.x * 128;
    const int wm = (wid >> 1) * 64;
    const int wn = (wid & 1) * 64;
    const int lr = lane & 15;
    const int quad = lane >> 4;

    const int r0 = tid >> 2, c0 = (tid & 3) * 8;
    const __hip_bfloat16* gA0 = A  + (size_t)(m0 + r0) * KPAD + c0;
    const __hip_bfloat16* gA1 = gA0 + (size_t)64 * KPAD;
    const __hip_bfloat16* gB0 = Bw + (size_t)(n0 + r0) * KPAD + c0;
    const __hip_bfloat16* gB1 = gB0 + (size_t)64 * KPAD;
    __hip_bfloat16* lA0 = As + wid * 512;
    __hip_bfloat16* lA1 = As + 2048 + wid * 512;
    __hip_bfloat16* lB0 = Bs + wid * 512;
    __hip_bfloat16* lB1 = Bs + 2048 + wid * 512;

    f32x4 acc[4][4] = {};

    const int kBeg = blockIdx.z * kchunk;
    const int kEnd = kBeg + kchunk;
    for (int k0 = kBeg; k0 < kEnd; k0 += 32) {
        __syncthreads();
        GLD_LDS(gA0 + k0, lA0);
        GLD_LDS(gA1 + k0, lA1);
        GLD_LDS(gB0 + k0, lB0);
        GLD_LDS(gB1 + k0, lB1);
        __syncthreads();
        bf16x8 af[4], bfr[4];
        #pragma unroll
        for (int mt = 0; mt < 4; mt++)
            af[mt] = *(const bf16x8*)(As + (wm + mt * 16 + lr) * 32 + quad * 8);
        #pragma unroll
        for (int nt = 0; nt < 4; nt++)
            bfr[nt] = *(const bf16x8*)(Bs + (wn + nt * 16 + lr) * 32 + quad * 8);
        #pragma unroll
        for (int mt = 0; mt < 4; mt++)
            #pragma unroll
            for (int nt = 0; nt < 4; nt++)
                acc[mt][nt] = __builtin_amdgcn_mfma_f32_16x16x32_bf16(
                    af[mt], bfr[nt], acc[mt][nt], 0, 0, 0);
    }

    // epilogue: C/D layout col = lane&15, row = quad*4 + reg
    float* Cs = Cm + (size_t)blockIdx.z * NPAD * NPAD;
    #pragma unroll
    for (int mt = 0; mt < 4; mt++) {
        #pragma unroll
        for (int nt = 0; nt < 4; nt++) {
            const int col = n0 + wn + nt * 16 + lr;
            const int rb  = m0 + wm + mt * 16 + quad * 4;
            #pragma unroll
            for (int r = 0; r < 4; r++)
                Cs[(size_t)(rb + r) * NPAD + col] = acc[mt][nt][r];
        }
    }
}

// ---------------------------------------------------------------------------
// Kernel 4: reduce split-K slabs + bias + relu, then FC2. One block per row.
__global__ __launch_bounds__(256) void fc2_kernel(
    const float* __restrict__ h1, const float* __restrict__ b1,
    const float* __restrict__ w2, const float* __restrict__ b2,
    float* __restrict__ out, int nslab)
{
    const int b = blockIdx.x;
    const int tid = threadIdx.x;
    float acc[NCLS];
    #pragma unroll
    for (int o = 0; o < NCLS; o++) acc[o] = 0.f;
    for (int n = tid; n < NFC1; n += 256) {
        float hv = b1[n];
        for (int s = 0; s < nslab; s++)
            hv += h1[(size_t)s * NPAD * NPAD + (size_t)b * NPAD + n];
        float h = fmaxf(hv, 0.f);
        #pragma unroll
        for (int o = 0; o < NCLS; o++)
            acc[o] = fmaf(h, w2[o * NFC1 + n], acc[o]);
    }
    __shared__ float red[4][NCLS];
    #pragma unroll
    for (int o = 0; o < NCLS; o++) {
        float v = acc[o];
        #pragma unroll
        for (int s = 32; s > 0; s >>= 1) v += __shfl_down(v, s);
        if ((tid & 63) == 0) red[tid >> 6][o] = v;
    }
    __syncthreads();
    if (tid < NCLS)
        out[b * NCLS + tid] = red[0][tid] + red[1][tid] + red[2][tid] +
                              red[3][tid] + b2[tid];
}

// ---------------------------------------------------------------------------
extern "C" void kernel_launch(void* const* d_in, const int* in_sizes, int n_in,
                              void* d_out, int out_size, void* d_ws, size_t ws_size,
                              hipStream_t stream)
{
    (void)n_in; (void)out_size;
    const float* x     = (const float*)d_in[0];
    const float* w_hs  = (const float*)d_in[1];
    const float* b_hs  = (const float*)d_in[2];
    const float* w_ls  = (const float*)d_in[3];
    const float* b_ls  = (const float*)d_in[4];
    const float* w_hi1 = (const float*)d_in[5];
    const float* b_hi1 = (const float*)d_in[6];
    const float* w_hi2 = (const float*)d_in[7];
    const float* b_hi2 = (const float*)d_in[8];
    const float* w_li1 = (const float*)d_in[9];
    const float* b_li1 = (const float*)d_in[10];
    const float* w_li2 = (const float*)d_in[11];
    const float* b_li2 = (const float*)d_in[12];
    const float* w_fc1 = (const float*)d_in[13];
    const float* b_fc1 = (const float*)d_in[14];
    const float* w_fc2 = (const float*)d_in[15];
    const float* b_fc2 = (const float*)d_in[16];
    float* out = (float*)d_out;

    const int B = in_sizes[0] / (T_LEN * C_CH);    // 2048

    char* ws = (char*)d_ws;
    const size_t featB = (size_t)B * KPAD * 2;         // 29.4 MB
    const size_t wbB   = (size_t)NPAD * KPAD * 2;      // 29.4 MB
    const size_t slabB = (size_t)NPAD * NPAD * 4;      // 16.8 MB
    const size_t xtB   = (size_t)T_LEN * C_CH * B * 4; // 51.9 MB
    const size_t base2 = featB + wbB;

    __hip_bfloat16* feat = (__hip_bfloat16*)ws;
    __hip_bfloat16* wb   = (__hip_bfloat16*)(ws + featB);
    float* h1            = (float*)(ws + base2);

    const int sk = (ws_size >= base2 + 4 * slabB) ? 4 : 2;
    const bool use_xt = (ws_size >= base2 + sk * slabB + xtB);
    float* xT = (float*)(ws + base2 + sk * slabB);

    pad_w_kernel<<<dim3((NPAD * 896) / 256), 256, 0, stream>>>(w_fc1, wb);

    const float* cx = x;
    int ts = C_CH, bsi = T_LEN * C_CH, cs = 1;
    if (use_xt) {
        transpose_kernel<<<dim3(99, B / 64), 256, 0, stream>>>(x, xT, B);
        cx = xT; ts = C_CH * B; bsi = 1; cs = B;
    }
    conv_fused_kernel<<<dim3(B / 64, C_CH, 2), 64, 0, stream>>>(
        cx, ts, bsi, cs, w_hs, b_hs, w_ls, b_ls,
        w_hi1, b_hi1, w_hi2, b_hi2, w_li1, b_li1, w_li2, b_li2, feat);
    gemm_kernel<<<dim3(NPAD / 128, B / 128, sk), 256, 0, stream>>>(
        feat, wb, h1, KPAD / sk);
    fc2_kernel<<<dim3(B), 256, 0, stream>>>(h1, b_fc1, w_fc2, b_fc2, out, sk);
}